// Round 4
// baseline (932.382 us; speedup 1.0000x reference)
//
#include <hip/hip_runtime.h>
#include <hip/hip_fp16.h>

#define N_NODES    100000
#define N_EDGES    3200000
#define IN_DIM     128
#define EMB        32
#define NUM_GRAPHS 256

#define FB         512       // coarse buckets (391 used: bucket = dst >> 8)
#define F1_EPB     8192      // edges per fill block
#define F1_BLOCKS  391       // ceil(N_EDGES / F1_EPB)
#define NBUCKETS   391       // ceil(N_NODES / 256)

// ---------------------------------------------------------------------------
// Kernel 1: xw = x @ W1 -> fp16  (x: [N,128], W1: [128,32])
// ---------------------------------------------------------------------------
__global__ __launch_bounds__(256) void k_xw(const float* __restrict__ x,
                                            const float* __restrict__ W1,
                                            __half* __restrict__ xwh) {
    __shared__ float Ws[IN_DIM * EMB];
    for (int i = threadIdx.x; i < IN_DIM * EMB; i += 256) Ws[i] = W1[i];
    __syncthreads();
    int row = blockIdx.x * 8 + (threadIdx.x >> 5);
    int col = threadIdx.x & 31;
    if (row >= N_NODES) return;
    const float4* xr = (const float4*)(x + (size_t)row * IN_DIM);
    float acc = 0.f;
#pragma unroll
    for (int k4 = 0; k4 < IN_DIM / 4; ++k4) {
        float4 xv = xr[k4];
        int k = k4 * 4;
        acc += xv.x * Ws[(k + 0) * EMB + col];
        acc += xv.y * Ws[(k + 1) * EMB + col];
        acc += xv.z * Ws[(k + 2) * EMB + col];
        acc += xv.w * Ws[(k + 3) * EMB + col];
    }
    xwh[(size_t)row * EMB + col] = __float2half(acc);
}

// ---------------------------------------------------------------------------
// Coarse histogram: chist[dst>>8] (per-block LDS hist, few global atomics)
// ---------------------------------------------------------------------------
__global__ __launch_bounds__(512) void k_hist1(const int* __restrict__ ei,
                                               int* __restrict__ chist) {
    __shared__ int h[FB];
    int t = threadIdx.x;
    h[t] = 0;
    __syncthreads();
    int e0 = blockIdx.x * F1_EPB;
    for (int k = t; k < F1_EPB; k += 512) {
        int e = e0 + k;
        if (e < N_EDGES) atomicAdd(&h[ei[N_EDGES + e] >> 8], 1);
    }
    __syncthreads();
    if (h[t]) atomicAdd(&chist[t], h[t]);
}

// ---------------------------------------------------------------------------
// Exclusive scan of coarse counts -> cbase (kept) + gcursor (fill1 mutates)
// ---------------------------------------------------------------------------
__global__ __launch_bounds__(512) void k_scanc(const int* __restrict__ chist,
                                               int* __restrict__ cbase,
                                               int* __restrict__ gcursor) {
    __shared__ int sc[FB];
    int t = threadIdx.x;
    int v = chist[t];
    sc[t] = v;
    __syncthreads();
    for (int off = 1; off < FB; off <<= 1) {
        int u = (t >= off) ? sc[t - off] : 0;
        __syncthreads();
        sc[t] += u;
        __syncthreads();
    }
    int excl = sc[t] - v;
    cbase[t] = excl;
    gcursor[t] = excl;
}

// ---------------------------------------------------------------------------
// Fill: group edges by coarse bucket, direct global placement.
// rec = (dst&255)<<24 | src (src < 2^17). base[b] reserved BEFORE placement,
// so the final address is known at write time — no staging, no binary search.
// Writes cluster into ~84 B runs private to this block -> writeback ~ payload.
// ---------------------------------------------------------------------------
__global__ __launch_bounds__(512) void k_fill1(const int* __restrict__ ei,
                                               int* __restrict__ gcursor,
                                               unsigned int* __restrict__ recs) {
    __shared__ int hist[FB];
    __shared__ int base[FB];
    __shared__ int lcur[FB];
    int t = threadIdx.x;
    hist[t] = 0;
    lcur[t] = 0;
    __syncthreads();
    int e0 = blockIdx.x * F1_EPB;
    int s[16], d[16];
#pragma unroll
    for (int k = 0; k < 16; ++k) {
        int e = e0 + k * 512 + t;
        if (e < N_EDGES) {
            s[k] = ei[e];
            d[k] = ei[N_EDGES + e];
            atomicAdd(&hist[d[k] >> 8], 1);
        } else {
            d[k] = -1;
        }
    }
    __syncthreads();
    if (hist[t]) base[t] = atomicAdd(&gcursor[t], hist[t]);
    __syncthreads();
#pragma unroll
    for (int k = 0; k < 16; ++k) {
        if (d[k] >= 0) {
            int b = d[k] >> 8;
            int pos = base[b] + atomicAdd(&lcur[b], 1);
            recs[pos] = ((unsigned int)(d[k] & 255) << 24) | (unsigned int)s[k];
        }
    }
}

// ---------------------------------------------------------------------------
// Per-bucket degree histogram -> dinv (replaces exact sort + rowstart)
// ---------------------------------------------------------------------------
__global__ __launch_bounds__(256) void k_dinv(const unsigned int* __restrict__ recs,
                                              const int* __restrict__ cbase,
                                              const int* __restrict__ chist,
                                              float* __restrict__ dinv) {
    __shared__ int h2[256];
    int t = threadIdx.x, b = blockIdx.x;
    h2[t] = 0;
    __syncthreads();
    int seg0 = cbase[b], cnt = chist[b];
    for (int j = t; j < cnt; j += 256)
        atomicAdd(&h2[recs[seg0 + j] >> 24], 1);
    __syncthreads();
    int node = (b << 8) + t;
    if (node < N_NODES) dinv[node] = rsqrtf((float)h2[t] + 1.0f);
}

// ---------------------------------------------------------------------------
// counts via binary search on sorted batch (no atomics)
// ---------------------------------------------------------------------------
__global__ __launch_bounds__(256) void k_bounds(const int* __restrict__ batch,
                                                float* __restrict__ counts) {
    int g = threadIdx.x;
    int lo = 0, hi = N_NODES;
    while (lo < hi) { int m = (lo + hi) >> 1; if (batch[m] < g) lo = m + 1; else hi = m; }
    int a = lo;
    lo = 0; hi = N_NODES;
    int g1 = g + 1;
    while (lo < hi) { int m = (lo + hi) >> 1; if (batch[m] < g1) lo = m + 1; else hi = m; }
    counts[g] = (float)(lo - a);
}

// ---------------------------------------------------------------------------
// Bucket accumulate: one block per 256-node bucket. 32 KB LDS fp32 accumulator;
// each 32-lane group processes one record: gather xwh[src] (64 B line),
// ds_add_f32 into acc[dst][c] (bank==lane, conflict-free in-group).
// Epilogue: self-loop + tanh + sorted-batch pool, all fused (no agg in HBM).
// ---------------------------------------------------------------------------
__global__ __launch_bounds__(512) void k_bucket(const unsigned int* __restrict__ recs,
                                                const int* __restrict__ cbase,
                                                const int* __restrict__ chist,
                                                const __half* __restrict__ xwh,
                                                const float* __restrict__ dinv,
                                                const int* __restrict__ batch,
                                                const float* __restrict__ b1,
                                                float* __restrict__ sums) {
    __shared__ float acc[256 * EMB];   // 32 KB
    int t = threadIdx.x, b = blockIdx.x;
    for (int i = t; i < 256 * EMB; i += 512) acc[i] = 0.f;
    __syncthreads();
    int seg0 = cbase[b], cnt = chist[b];
    int g = t >> 5, c = t & 31;
    for (int j = g; j < cnt; j += 16) {
        unsigned int r = recs[seg0 + j];
        int s = (int)(r & 0x1FFFF);
        int d = (int)(r >> 24);
        float w = dinv[s];
        float v = __half2float(xwh[s * EMB + c]);
        atomicAdd(&acc[d * EMB + c], v * w);
    }
    __syncthreads();
    int node0 = b << 8;
    // self-loop + tanh, in place
    for (int r = t >> 5; r < 256; r += 16) {
        int node = node0 + r;
        if (node < N_NODES) {
            float di = dinv[node];
            float h = tanhf((acc[r * EMB + c] + __half2float(xwh[node * EMB + c]) * di) * di + b1[c]);
            acc[r * EMB + c] = h;
        }
    }
    __syncthreads();
    // pool: wave w reduces rows 32w..32w+31, merging runs of equal graph id
    int w = t >> 6;
    int lane = t & 63;
    if (lane < 32) {
        int cc = lane;
        int r0 = w * 32;
        int rr = r0;
        while (rr < r0 + 32) {
            int node = node0 + rr;
            if (node >= N_NODES) break;
            int g0 = batch[node];
            float a = acc[rr * EMB + cc];
            int r2 = rr + 1;
            while (r2 < r0 + 32 && node0 + r2 < N_NODES && batch[node0 + r2] == g0) {
                a += acc[r2 * EMB + cc];
                ++r2;
            }
            atomicAdd(&sums[g0 * EMB + cc], a);
            rr = r2;
        }
    }
}

// ---------------------------------------------------------------------------
// head: out[g] = [sums, means] @ Wout + bout
// ---------------------------------------------------------------------------
__global__ __launch_bounds__(64) void k_out(const float* __restrict__ sums,
                                            const float* __restrict__ counts,
                                            const float* __restrict__ Wout,
                                            const float* __restrict__ bout,
                                            float* __restrict__ out) {
    int g = blockIdx.x * 64 + threadIdx.x;
    if (g >= NUM_GRAPHS) return;
    float inv = 1.0f / fmaxf(counts[g], 1.0f);
    float acc = bout[0];
#pragma unroll
    for (int c = 0; c < EMB; ++c) {
        float s = sums[g * EMB + c];
        acc += s * Wout[c] + s * inv * Wout[EMB + c];
    }
    out[g] = acc;
}

extern "C" void kernel_launch(void* const* d_in, const int* in_sizes, int n_in,
                              void* d_out, int out_size, void* d_ws, size_t ws_size,
                              hipStream_t stream) {
    const float* x     = (const float*)d_in[0];
    const int*   ei    = (const int*)d_in[1];   // [2, E]
    const int*   batch = (const int*)d_in[2];   // [N], sorted
    const float* W1    = (const float*)d_in[3];
    const float* b1    = (const float*)d_in[4];
    const float* Wout  = (const float*)d_in[5];
    const float* bout  = (const float*)d_in[6];
    float* out = (float*)d_out;

    // workspace (~20 MB)
    char* ws = (char*)d_ws;
    __half* xwh        = (__half*)ws;       ws += (size_t)N_NODES * EMB * sizeof(__half);  // 6.4 MB
    unsigned int* recs = (unsigned int*)ws; ws += (size_t)N_EDGES * sizeof(int);           // 12.8 MB
    float* dinv        = (float*)ws;        ws += (size_t)N_NODES * sizeof(float);         // 0.4 MB
    int*   chist       = (int*)ws;          ws += FB * sizeof(int);
    int*   cbase       = (int*)ws;          ws += FB * sizeof(int);
    int*   gcursor     = (int*)ws;          ws += FB * sizeof(int);
    float* sums        = (float*)ws;        ws += (size_t)NUM_GRAPHS * EMB * sizeof(float);
    float* counts      = (float*)ws;

    hipMemsetAsync(chist, 0, FB * sizeof(int), stream);
    hipMemsetAsync(sums, 0, (size_t)NUM_GRAPHS * EMB * sizeof(float), stream);

    k_xw    <<<(N_NODES + 7) / 8, 256, 0, stream>>>(x, W1, xwh);
    k_hist1 <<<F1_BLOCKS, 512, 0, stream>>>(ei, chist);
    k_scanc <<<1, 512, 0, stream>>>(chist, cbase, gcursor);
    k_fill1 <<<F1_BLOCKS, 512, 0, stream>>>(ei, gcursor, recs);
    k_dinv  <<<NBUCKETS, 256, 0, stream>>>(recs, cbase, chist, dinv);
    k_bounds<<<1, 256, 0, stream>>>(batch, counts);
    k_bucket<<<NBUCKETS, 512, 0, stream>>>(recs, cbase, chist, xwh, dinv, batch, b1, sums);
    k_out   <<<(NUM_GRAPHS + 63) / 64, 64, 0, stream>>>(sums, counts, Wout, bout, out);
}

// Round 5
// 251.969 us; speedup vs baseline: 3.7004x; 3.7004x over previous
//
#include <hip/hip_runtime.h>
#include <hip/hip_fp16.h>

#define N_NODES    100000
#define N_EDGES    3200000
#define IN_DIM     128
#define EMB        32
#define NUM_GRAPHS 256

#define FB         512       // coarse buckets (391 used: bucket = dst >> 8)
#define F1_EPB     8192      // edges per fill/hist block
#define F1_BLOCKS  391       // ceil(N_EDGES / F1_EPB)
#define NBUCKETS   391       // ceil(N_NODES / 256)
#define CAP        10240     // fill2 LDS staging capacity (mean 8192, +22 sigma)

typedef _Float16 half8 __attribute__((ext_vector_type(8)));
typedef float floatx4 __attribute__((ext_vector_type(4)));

// ---------------------------------------------------------------------------
// Kernel 1: xw = x @ W1 -> fp16, via MFMA 16x16x32_f16. One wave = 16 rows.
// A[m=lane&15][k=quad*8+j] from x (fp32->fp16 in regs); B staged fp16 in LDS
// once, read into regs once per wave. No LDS in the K loop.
// Block 0 also zero-inits chist (safe: consumed by the NEXT kernel).
// ---------------------------------------------------------------------------
__global__ __launch_bounds__(256) void k_xw(const float* __restrict__ x,
                                            const float* __restrict__ W1,
                                            __half* __restrict__ xwh,
                                            int* __restrict__ chist) {
    if (blockIdx.x == 0)
        for (int i = threadIdx.x; i < FB; i += 256) chist[i] = 0;
    __shared__ _Float16 Wh[IN_DIM * EMB];   // 8 KB
    for (int i = threadIdx.x; i < IN_DIM * EMB; i += 256)
        Wh[i] = (_Float16)W1[i];
    __syncthreads();
    int wave = threadIdx.x >> 6;
    int lane = threadIdx.x & 63;
    int m = lane & 15, quad = lane >> 4;
    int row0 = (blockIdx.x * 4 + wave) * 16;
    if (row0 >= N_NODES) return;
    // B fragments: bfrag[ntile][kstep][j] = W[ks*32+quad*8+j][nt*16+m]
    half8 bfrag[2][4];
#pragma unroll
    for (int nt = 0; nt < 2; ++nt)
#pragma unroll
        for (int ks = 0; ks < 4; ++ks)
#pragma unroll
            for (int j = 0; j < 8; ++j)
                bfrag[nt][ks][j] = Wh[(ks * 32 + quad * 8 + j) * EMB + nt * 16 + m];
    const float* xr = x + (size_t)(row0 + m) * IN_DIM + quad * 8;
    floatx4 c0 = {0.f, 0.f, 0.f, 0.f}, c1 = {0.f, 0.f, 0.f, 0.f};
#pragma unroll
    for (int ks = 0; ks < 4; ++ks) {
        float4 a0 = *(const float4*)(xr + ks * 32);
        float4 a1 = *(const float4*)(xr + ks * 32 + 4);
        half8 af;
        af[0] = (_Float16)a0.x; af[1] = (_Float16)a0.y;
        af[2] = (_Float16)a0.z; af[3] = (_Float16)a0.w;
        af[4] = (_Float16)a1.x; af[5] = (_Float16)a1.y;
        af[6] = (_Float16)a1.z; af[7] = (_Float16)a1.w;
        c0 = __builtin_amdgcn_mfma_f32_16x16x32_f16(af, bfrag[0][ks], c0, 0, 0, 0);
        c1 = __builtin_amdgcn_mfma_f32_16x16x32_f16(af, bfrag[1][ks], c1, 0, 0, 0);
    }
    // C/D: col = lane&15, row = quad*4 + reg
#pragma unroll
    for (int r = 0; r < 4; ++r) {
        int ro = row0 + quad * 4 + r;
        xwh[(size_t)ro * EMB + m]      = __float2half(c0[r]);
        xwh[(size_t)ro * EMB + 16 + m] = __float2half(c1[r]);
    }
}

// ---------------------------------------------------------------------------
// Coarse histogram of dst>>8 (per-block LDS hist, few global atomics)
// ---------------------------------------------------------------------------
__global__ __launch_bounds__(512) void k_hist1(const int* __restrict__ ei,
                                               int* __restrict__ chist) {
    __shared__ int h[FB];
    int t = threadIdx.x;
    h[t] = 0;
    __syncthreads();
    int e0 = blockIdx.x * F1_EPB;
    for (int k = t; k < F1_EPB; k += 512) {
        int e = e0 + k;
        if (e < N_EDGES) atomicAdd(&h[ei[N_EDGES + e] >> 8], 1);
    }
    __syncthreads();
    if (h[t]) atomicAdd(&chist[t], h[t]);
}

// ---------------------------------------------------------------------------
// Aux (2 blocks): block 0 = exclusive scan of chist -> cbase + gcursor;
// block 1 = zero sums + per-graph counts via binary search on sorted batch.
// ---------------------------------------------------------------------------
__global__ __launch_bounds__(512) void k_aux(const int* __restrict__ chist,
                                             int* __restrict__ cbase,
                                             int* __restrict__ gcursor,
                                             const int* __restrict__ batch,
                                             float* __restrict__ sums,
                                             float* __restrict__ counts) {
    int t = threadIdx.x;
    if (blockIdx.x == 0) {
        __shared__ int sc[FB];
        int v = chist[t];
        sc[t] = v;
        __syncthreads();
        for (int off = 1; off < FB; off <<= 1) {
            int u = (t >= off) ? sc[t - off] : 0;
            __syncthreads();
            sc[t] += u;
            __syncthreads();
        }
        int excl = sc[t] - v;
        cbase[t] = excl;
        gcursor[t] = excl;
    } else {
        for (int i = t; i < NUM_GRAPHS * EMB; i += 512) sums[i] = 0.f;
        if (t < NUM_GRAPHS) {
            int lo = 0, hi = N_NODES;
            while (lo < hi) { int mid = (lo + hi) >> 1; if (batch[mid] < t) lo = mid + 1; else hi = mid; }
            int a = lo;
            lo = 0; hi = N_NODES;
            int g1 = t + 1;
            while (lo < hi) { int mid = (lo + hi) >> 1; if (batch[mid] < g1) lo = mid + 1; else hi = mid; }
            counts[t] = (float)(lo - a);
        }
    }
}

// ---------------------------------------------------------------------------
// Fill: group edges by coarse bucket, direct global placement (bases reserved
// before writes -> ~84 B contiguous runs per (block,bucket), writeback~payload)
// rec = (dst&255)<<24 | src
// ---------------------------------------------------------------------------
__global__ __launch_bounds__(512) void k_fill1(const int* __restrict__ ei,
                                               int* __restrict__ gcursor,
                                               unsigned int* __restrict__ recs) {
    __shared__ int hist[FB];
    __shared__ int base[FB];
    __shared__ int lcur[FB];
    int t = threadIdx.x;
    hist[t] = 0;
    lcur[t] = 0;
    __syncthreads();
    int e0 = blockIdx.x * F1_EPB;
    int s[16], d[16];
#pragma unroll
    for (int k = 0; k < 16; ++k) {
        int e = e0 + k * 512 + t;
        if (e < N_EDGES) {
            s[k] = ei[e];
            d[k] = ei[N_EDGES + e];
            atomicAdd(&hist[d[k] >> 8], 1);
        } else {
            d[k] = -1;
        }
    }
    __syncthreads();
    if (hist[t]) base[t] = atomicAdd(&gcursor[t], hist[t]);
    __syncthreads();
#pragma unroll
    for (int k = 0; k < 16; ++k) {
        if (d[k] >= 0) {
            int b = d[k] >> 8;
            int pos = base[b] + atomicAdd(&lcur[b], 1);
            recs[pos] = ((unsigned int)(d[k] & 255) << 24) | (unsigned int)s[k];
        }
    }
}

// ---------------------------------------------------------------------------
// Fill2: one block per bucket. Exact counting sort by dst&255 (records staged
// in LDS), emits edge_src + rowstart + dinv, then scales xwh rows IN PLACE by
// dinv (so gather needs no per-edge dinv lookup).
// ---------------------------------------------------------------------------
__global__ __launch_bounds__(512) void k_fill2(const unsigned int* __restrict__ recs,
                                               const int* __restrict__ cbase,
                                               const int* __restrict__ chist,
                                               int* __restrict__ edge_src,
                                               int* __restrict__ rowstart,
                                               float* __restrict__ dinv,
                                               __half* __restrict__ xwh) {
    __shared__ unsigned int lbuf[CAP];          // 40 KB
    __shared__ int h2[256], cur2[256], sc[256];
    __shared__ float dv[256];
    int t = threadIdx.x, b = blockIdx.x;
    if (t < 256) h2[t] = 0;
    __syncthreads();
    int seg0 = cbase[b], cnt = chist[b];
    for (int j = t; j < cnt; j += 512) {
        unsigned int r = recs[seg0 + j];
        if (j < CAP) lbuf[j] = r;
        atomicAdd(&h2[r >> 24], 1);
    }
    __syncthreads();
    // exclusive scan of 256 (threads >=256 idle but hit the barriers)
    int v = 0;
    if (t < 256) { v = h2[t]; sc[t] = v; }
    __syncthreads();
    for (int off = 1; off < 256; off <<= 1) {
        int u = 0;
        if (t < 256 && t >= off) u = sc[t - off];
        __syncthreads();
        if (t < 256) sc[t] += u;
        __syncthreads();
    }
    int node0 = b << 8;
    if (t < 256) {
        int excl = sc[t] - v;
        cur2[t] = excl;
        float dval = rsqrtf((float)v + 1.0f);
        dv[t] = dval;
        int node = node0 + t;
        if (node < N_NODES) {
            rowstart[node] = seg0 + excl;
            dinv[node] = dval;
        }
    }
    if (b == 0 && t == 0) rowstart[N_NODES] = N_EDGES;
    __syncthreads();
    for (int j = t; j < cnt; j += 512) {
        unsigned int r = (j < CAP) ? lbuf[j] : recs[seg0 + j];
        int p = atomicAdd(&cur2[r >> 24], 1);
        edge_src[seg0 + p] = (int)(r & 0x00FFFFFF);
    }
    // scale xwh rows of this bucket in place: xwh[i] *= dinv[i]
    for (int idx = t; idx < 256 * EMB; idx += 512) {
        int node = node0 + (idx >> 5);
        if (node < N_NODES) {
            size_t a = (size_t)node * EMB + (idx & 31);
            xwh[a] = __float2half(__half2float(xwh[a]) * dv[idx >> 5]);
        }
    }
}

// ---------------------------------------------------------------------------
// Fused gather: acc = sum_in xws[s] (pre-scaled payload, 8-edge unroll),
// h = tanh((acc + xws[i]) * dinv[i] + b1), sorted-batch pooled into sums.
// 12500 blocks x 8 nodes -> high occupancy, latency hidden.
// ---------------------------------------------------------------------------
__global__ __launch_bounds__(256) void k_gather(const __half* __restrict__ xws,
                                                const float* __restrict__ dinv,
                                                const int* __restrict__ rowstart,
                                                const int* __restrict__ edge_src,
                                                const int* __restrict__ batch,
                                                const float* __restrict__ b1,
                                                float* __restrict__ sums) {
    int r = threadIdx.x >> 5;
    int c = threadIdx.x & 31;
    int i = blockIdx.x * 8 + r;
    float di = dinv[i];
    int e0 = rowstart[i], e1 = rowstart[i + 1];
    float acc = 0.f;
    int e = e0;
    for (; e + 7 < e1; e += 8) {
        int s0 = edge_src[e],     s1 = edge_src[e + 1];
        int s2 = edge_src[e + 2], s3 = edge_src[e + 3];
        int s4 = edge_src[e + 4], s5 = edge_src[e + 5];
        int s6 = edge_src[e + 6], s7 = edge_src[e + 7];
        float v0 = __half2float(xws[s0 * EMB + c]);
        float v1 = __half2float(xws[s1 * EMB + c]);
        float v2 = __half2float(xws[s2 * EMB + c]);
        float v3 = __half2float(xws[s3 * EMB + c]);
        float v4 = __half2float(xws[s4 * EMB + c]);
        float v5 = __half2float(xws[s5 * EMB + c]);
        float v6 = __half2float(xws[s6 * EMB + c]);
        float v7 = __half2float(xws[s7 * EMB + c]);
        acc += ((v0 + v1) + (v2 + v3)) + ((v4 + v5) + (v6 + v7));
    }
    for (; e < e1; ++e) {
        int s = edge_src[e];
        acc += __half2float(xws[s * EMB + c]);
    }
    float h = tanhf((acc + __half2float(xws[i * EMB + c])) * di + b1[c]);

    __shared__ float hs[8][EMB];
    __shared__ int gb[8];
    hs[r][c] = h;
    if (c == 0) gb[r] = batch[i];
    __syncthreads();
    if (threadIdx.x < 32) {
        int cc = threadIdx.x;
        int rr = 0;
        while (rr < 8) {
            int g0 = gb[rr];
            float a = hs[rr][cc];
            int r2 = rr + 1;
            while (r2 < 8 && gb[r2] == g0) { a += hs[r2][cc]; ++r2; }
            atomicAdd(&sums[g0 * EMB + cc], a);
            rr = r2;
        }
    }
}

// ---------------------------------------------------------------------------
// head: out[g] = [sums, means] @ Wout + bout
// ---------------------------------------------------------------------------
__global__ __launch_bounds__(64) void k_out(const float* __restrict__ sums,
                                            const float* __restrict__ counts,
                                            const float* __restrict__ Wout,
                                            const float* __restrict__ bout,
                                            float* __restrict__ out) {
    int g = blockIdx.x * 64 + threadIdx.x;
    if (g >= NUM_GRAPHS) return;
    float inv = 1.0f / fmaxf(counts[g], 1.0f);
    float acc = bout[0];
#pragma unroll
    for (int c = 0; c < EMB; ++c) {
        float s = sums[g * EMB + c];
        acc += s * Wout[c] + s * inv * Wout[EMB + c];
    }
    out[g] = acc;
}

extern "C" void kernel_launch(void* const* d_in, const int* in_sizes, int n_in,
                              void* d_out, int out_size, void* d_ws, size_t ws_size,
                              hipStream_t stream) {
    const float* x     = (const float*)d_in[0];
    const int*   ei    = (const int*)d_in[1];   // [2, E]
    const int*   batch = (const int*)d_in[2];   // [N], sorted
    const float* W1    = (const float*)d_in[3];
    const float* b1    = (const float*)d_in[4];
    const float* Wout  = (const float*)d_in[5];
    const float* bout  = (const float*)d_in[6];
    float* out = (float*)d_out;

    // workspace (~33 MB)
    char* ws = (char*)d_ws;
    __half* xwh        = (__half*)ws;       ws += (size_t)N_NODES * EMB * sizeof(__half);  // 6.4 MB
    unsigned int* recs = (unsigned int*)ws; ws += (size_t)N_EDGES * sizeof(int);           // 12.8 MB
    int*   edge_src    = (int*)ws;          ws += (size_t)N_EDGES * sizeof(int);           // 12.8 MB
    int*   rowstart    = (int*)ws;          ws += (size_t)(N_NODES + 4) * sizeof(int);     // 0.4 MB
    float* dinv        = (float*)ws;        ws += (size_t)N_NODES * sizeof(float);         // 0.4 MB
    int*   chist       = (int*)ws;          ws += FB * sizeof(int);
    int*   cbase       = (int*)ws;          ws += FB * sizeof(int);
    int*   gcursor     = (int*)ws;          ws += FB * sizeof(int);
    float* sums        = (float*)ws;        ws += (size_t)NUM_GRAPHS * EMB * sizeof(float);
    float* counts      = (float*)ws;

    k_xw    <<<(N_NODES + 63) / 64, 256, 0, stream>>>(x, W1, xwh, chist);
    k_hist1 <<<F1_BLOCKS, 512, 0, stream>>>(ei, chist);
    k_aux   <<<2, 512, 0, stream>>>(chist, cbase, gcursor, batch, sums, counts);
    k_fill1 <<<F1_BLOCKS, 512, 0, stream>>>(ei, gcursor, recs);
    k_fill2 <<<NBUCKETS, 512, 0, stream>>>(recs, cbase, chist, edge_src, rowstart, dinv, xwh);
    k_gather<<<N_NODES / 8, 256, 0, stream>>>(xwh, dinv, rowstart, edge_src, batch, b1, sums);
    k_out   <<<(NUM_GRAPHS + 63) / 64, 64, 0, stream>>>(sums, counts, Wout, bout, out);
}